// Round 2
// baseline (209.507 us; speedup 1.0000x reference)
//
#include <hip/hip_runtime.h>

// Problem constants (from reference)
#define N_NODES   1048576
#define N_GRAPHS  4096
#define NPG       256      // nodes per graph (contiguous batch segments)
#define F_IN      16
#define HID       32
#define NODES_PER_THREAD 4 // one wave (64 lanes) covers exactly one graph

// d_ws layout (floats):
//  [0    .. 511 ] : WzT[c*16+r] = (W_z[0,0]+W_z[1,0])[r][c], r<16
//  [512  .. 1023] : WhT[c*16+r] = (W_h[0,0]+W_h[1,0])[r][c], r<16
//  [1024 .. 1055] : b_z
//  [1056 .. 1087] : b_h
//  [1088 .. 1119] : W_lin
//  [1120]         : b_lin
#define WS_FLOATS 1121

__global__ __launch_bounds__(512) void prep_kernel(
    const float* __restrict__ Wz, const float* __restrict__ bz,
    const float* __restrict__ Wh, const float* __restrict__ bh,
    const float* __restrict__ Wlin, const float* __restrict__ blin,
    float* __restrict__ w)
{
    const int t = threadIdx.x;           // 512 threads, 1 block
    {
        const int c = t >> 4;            // 0..31
        const int r = t & 15;            // 0..15
        const int src = r * HID + c;     // W[k,0,r,c], k-stride = 48*32 = 1536
        w[t]       = Wz[src] + Wz[1536 + src];
        w[512 + t] = Wh[src] + Wh[1536 + src];
    }
    if (t < HID) {
        w[1024 + t] = bz[t];
        w[1056 + t] = bh[t];
        w[1088 + t] = Wlin[t];
    }
    if (t == 0) w[1120] = blin[0];
}

// Core body: each thread handles 4 consecutive nodes; each wave handles one
// graph (64 lanes x 4 nodes = 256 = NPG). Weights-major loop: 32 weight
// floats per column-pair are loaded once (uniform -> SGPR) and reused for
// 4 nodes x 16 FMAs each. w points at the WS layout above (global or LDS).
__device__ __forceinline__ void gcn_body(
    const float* __restrict__ x, const float* w, float* __restrict__ out,
    int block_id, int t)
{
    const int base_node = block_id * (NPG * 4) + t * NODES_PER_THREAD;
    // Load 4 nodes x 16 features = 64 contiguous floats as 16 float4.
    float xv[NODES_PER_THREAD * F_IN];
    const float4* xp = (const float4*)(x + (size_t)base_node * F_IN);
#pragma unroll
    for (int i = 0; i < 16; ++i) {
        const float4 v = xp[i];
        xv[i * 4 + 0] = v.x; xv[i * 4 + 1] = v.y;
        xv[i * 4 + 2] = v.z; xv[i * 4 + 3] = v.w;
    }

    float acc[NODES_PER_THREAD] = {0.0f, 0.0f, 0.0f, 0.0f};

#pragma unroll 2
    for (int c = 0; c < HID; ++c) {
        // Uniform weight loads -> SGPRs (s_load), reused across 4 nodes.
        float wzc[F_IN], whc[F_IN];
#pragma unroll
        for (int r = 0; r < F_IN; ++r) {
            wzc[r] = w[c * 16 + r];
            whc[r] = w[512 + c * 16 + r];
        }
        const float bzc = w[1024 + c];
        const float bhc = w[1056 + c];
        const float wlc = w[1088 + c];

#pragma unroll
        for (int n = 0; n < NODES_PER_THREAD; ++n) {
            float az = bzc, ah = bhc;
#pragma unroll
            for (int r = 0; r < F_IN; ++r) {
                az = fmaf(xv[n * 16 + r], wzc[r], az);
                ah = fmaf(xv[n * 16 + r], whc[r], ah);
            }
            // (1 - sigmoid(az)) = 1/(1+e^az), overflow-safe.
            const float omz = 1.0f / (1.0f + __expf(az));
            // tanh(ah) = 1 - 2/(e^{2ah}+1), overflow-safe.
            const float eh = __expf(2.0f * ah);
            const float th = 1.0f - 2.0f / (eh + 1.0f);
            float H = omz * th;
            H = H > 0.0f ? H : 0.0f;           // relu
            acc[n] = fmaf(H, wlc, acc[n]);     // dot with W_lin
        }
    }

    // Per-wave reduction: one wave == one graph. No LDS, no barrier.
    float s = (acc[0] + acc[1]) + (acc[2] + acc[3]);
#pragma unroll
    for (int off = 32; off > 0; off >>= 1)
        s += __shfl_down(s, off, 64);
    if ((t & 63) == 0) {
        const int g = block_id * 4 + (t >> 6);
        out[g] = s * (1.0f / (float)NPG) + w[1120];
    }
}

// Main path: weights precomputed in d_ws.
__global__ __launch_bounds__(256) void gcn_main(
    const float* __restrict__ x, const float* __restrict__ w, float* __restrict__ out)
{
    gcn_body(x, w, out, blockIdx.x, threadIdx.x);
}

// Fallback if ws_size is too small: build summed weights in LDS per block.
__global__ __launch_bounds__(256) void gcn_main_lds(
    const float* __restrict__ x,
    const float* __restrict__ Wz, const float* __restrict__ bz,
    const float* __restrict__ Wh, const float* __restrict__ bh,
    const float* __restrict__ Wlin, const float* __restrict__ blin,
    float* __restrict__ out)
{
    __shared__ float w[WS_FLOATS];
    const int t = threadIdx.x;
#pragma unroll
    for (int i = t; i < 512; i += 256) {
        const int c = i >> 4, r = i & 15;
        const int src = r * HID + c;
        w[i]       = Wz[src] + Wz[1536 + src];
        w[512 + i] = Wh[src] + Wh[1536 + src];
    }
    if (t < HID) { w[1024 + t] = bz[t]; w[1056 + t] = bh[t]; w[1088 + t] = Wlin[t]; }
    if (t == 0)  w[1120] = blin[0];
    __syncthreads();
    gcn_body(x, w, out, blockIdx.x, t);
}

extern "C" void kernel_launch(void* const* d_in, const int* in_sizes, int n_in,
                              void* d_out, int out_size, void* d_ws, size_t ws_size,
                              hipStream_t stream)
{
    // setup_inputs order:
    // 0:x 1:edge_index 2:edge_weight 3:batch 4:W_z 5:b_z 6:W_r 7:b_r 8:W_h 9:b_h 10:W_lin 11:b_lin
    const float* x    = (const float*)d_in[0];
    const float* Wz   = (const float*)d_in[4];
    const float* bz   = (const float*)d_in[5];
    const float* Wh   = (const float*)d_in[8];
    const float* bh   = (const float*)d_in[9];
    const float* Wlin = (const float*)d_in[10];
    const float* blin = (const float*)d_in[11];
    float* out = (float*)d_out;

    const int n_blocks = N_NODES / (NPG * 4);  // 1024 blocks; 4 graphs/block

    if (ws_size >= WS_FLOATS * sizeof(float)) {
        float* w = (float*)d_ws;
        prep_kernel<<<1, 512, 0, stream>>>(Wz, bz, Wh, bh, Wlin, blin, w);
        gcn_main<<<n_blocks, 256, 0, stream>>>(x, w, out);
    } else {
        gcn_main_lds<<<n_blocks, 256, 0, stream>>>(x, Wz, bz, Wh, bh, Wlin, blin, out);
    }
}

// Round 3
// 204.054 us; speedup vs baseline: 1.0267x; 1.0267x over previous
//
#include <hip/hip_runtime.h>

// Problem constants (from reference)
#define N_NODES   1048576
#define N_GRAPHS  4096
#define NPG       256      // nodes per graph (contiguous batch segments)
#define F_IN      16
#define HID       32

// d_ws layout (floats):
//  [0    .. 511 ] : Wz_sum[r*32+c] = (W_z[0,0]+W_z[1,0])[r][c], r<16  (row-major)
//  [512  .. 1023] : Wh_sum[r*32+c]
//  [1024 .. 1055] : b_z
//  [1056 .. 1087] : b_h
//  [1088 .. 1119] : W_lin
//  [1120]         : b_lin
#define WS_FLOATS 1121

typedef __attribute__((ext_vector_type(8))) short short8v;  // 8 bf16 = 4 VGPR
typedef __attribute__((ext_vector_type(4))) float float4v;  // MFMA C/D

__device__ __forceinline__ unsigned short bf16_hi(float f) {
    unsigned u = __float_as_uint(f);
    unsigned r = u + 0x7FFFu + ((u >> 16) & 1u);   // round-to-nearest-even
    return (unsigned short)(r >> 16);
}
__device__ __forceinline__ float bf16_f32(unsigned short h) {
    return __uint_as_float(((unsigned)h) << 16);
}

__global__ __launch_bounds__(512) void prep_kernel(
    const float* __restrict__ Wz, const float* __restrict__ bz,
    const float* __restrict__ Wh, const float* __restrict__ bh,
    const float* __restrict__ Wlin, const float* __restrict__ blin,
    float* __restrict__ w)
{
    const int t = threadIdx.x;  // 512 threads, 1 block
    // rows r<16 of W[k,0]: element [r][c] at r*32+c == t; k-stride 48*32=1536
    w[t]       = Wz[t] + Wz[1536 + t];
    w[512 + t] = Wh[t] + Wh[1536 + t];
    if (t < HID) {
        w[1024 + t] = bz[t];
        w[1056 + t] = bh[t];
        w[1088 + t] = Wlin[t];
    }
    if (t == 0) w[1120] = blin[0];
}

// One block = one graph (256 nodes). Wave wv handles nodes [wv*64, wv*64+64)
// as 4 MFMA M-tiles of 16 nodes. mfma_f32_16x16x32_bf16, K padded 16->32.
// hi/lo bf16 split, 3 MFMAs per acc: Ah*Bh + Ah*Bl + Al*Bh.
// A layout: lane=(q<<4)|m holds A[m][k=q*8+j]; B: B[k=q*8+j][n=m];
// C/D: col=m, row=q*4+reg.  (HW-verified layouts.)
__device__ __forceinline__ void gcn_body(
    const float* __restrict__ x, const float* w, float* __restrict__ out,
    int g, int t)
{
    const int lane = t & 63;
    const int wv   = t >> 6;     // wave 0..3
    const int q    = lane >> 4;  // quad 0..3
    const int m    = lane & 15;

    // ---- Build B fragments (constant for whole kernel) ----
    short8v bz0h = {}, bz0l = {}, bz1h = {}, bz1l = {};
    short8v bh0h = {}, bh0l = {}, bh1h = {}, bh1l = {};
    if (q < 2) {
#pragma unroll
        for (int j = 0; j < 8; ++j) {
            const int k = q * 8 + j;   // k < 16 (real); quads 2,3 stay zero
            const float fz0 = w[k * 32 + m];
            const float fz1 = w[k * 32 + 16 + m];
            const float fh0 = w[512 + k * 32 + m];
            const float fh1 = w[512 + k * 32 + 16 + m];
            unsigned short h;
            h = bf16_hi(fz0); bz0h[j] = (short)h; bz0l[j] = (short)bf16_hi(fz0 - bf16_f32(h));
            h = bf16_hi(fz1); bz1h[j] = (short)h; bz1l[j] = (short)bf16_hi(fz1 - bf16_f32(h));
            h = bf16_hi(fh0); bh0h[j] = (short)h; bh0l[j] = (short)bf16_hi(fh0 - bf16_f32(h));
            h = bf16_hi(fh1); bh1h[j] = (short)h; bh1l[j] = (short)bf16_hi(fh1 - bf16_f32(h));
        }
    }

    // Per-lane column constants (col = m and m+16)
    const float bz0 = w[1024 + m], bz1 = w[1024 + 16 + m];
    const float bh0 = w[1056 + m], bh1 = w[1056 + 16 + m];
    const float wl0 = w[1088 + m], wl1 = w[1088 + 16 + m];

    const float* xg = x + ((size_t)g * NPG + wv * 64) * F_IN;

    float osum = 0.0f;
#pragma unroll
    for (int it = 0; it < 4; ++it) {
        // ---- A fragment: node = it*16 + m, features q*8..q*8+7 (q<2) ----
        short8v Ah = {}, Al = {};
        if (q < 2) {
            const float4* p = (const float4*)(xg + (it * 16 + m) * F_IN + q * 8);
            const float4 v0 = p[0], v1 = p[1];
            const float f[8] = { v0.x, v0.y, v0.z, v0.w, v1.x, v1.y, v1.z, v1.w };
#pragma unroll
            for (int j = 0; j < 8; ++j) {
                const unsigned short h = bf16_hi(f[j]);
                Ah[j] = (short)h;
                Al[j] = (short)bf16_hi(f[j] - bf16_f32(h));
            }
        }

        // ---- 4 accumulator tiles: Z cols 0-15, Z 16-31, H 0-15, H 16-31 ----
        float4v az0 = { bz0, bz0, bz0, bz0 };
        float4v az1 = { bz1, bz1, bz1, bz1 };
        float4v ah0 = { bh0, bh0, bh0, bh0 };
        float4v ah1 = { bh1, bh1, bh1, bh1 };

        az0 = __builtin_amdgcn_mfma_f32_16x16x32_bf16(Ah, bz0h, az0, 0, 0, 0);
        az1 = __builtin_amdgcn_mfma_f32_16x16x32_bf16(Ah, bz1h, az1, 0, 0, 0);
        ah0 = __builtin_amdgcn_mfma_f32_16x16x32_bf16(Ah, bh0h, ah0, 0, 0, 0);
        ah1 = __builtin_amdgcn_mfma_f32_16x16x32_bf16(Ah, bh1h, ah1, 0, 0, 0);
        az0 = __builtin_amdgcn_mfma_f32_16x16x32_bf16(Ah, bz0l, az0, 0, 0, 0);
        az1 = __builtin_amdgcn_mfma_f32_16x16x32_bf16(Ah, bz1l, az1, 0, 0, 0);
        ah0 = __builtin_amdgcn_mfma_f32_16x16x32_bf16(Ah, bh0l, ah0, 0, 0, 0);
        ah1 = __builtin_amdgcn_mfma_f32_16x16x32_bf16(Ah, bh1l, ah1, 0, 0, 0);
        az0 = __builtin_amdgcn_mfma_f32_16x16x32_bf16(Al, bz0h, az0, 0, 0, 0);
        az1 = __builtin_amdgcn_mfma_f32_16x16x32_bf16(Al, bz1h, az1, 0, 0, 0);
        ah0 = __builtin_amdgcn_mfma_f32_16x16x32_bf16(Al, bh0h, ah0, 0, 0, 0);
        ah1 = __builtin_amdgcn_mfma_f32_16x16x32_bf16(Al, bh1h, ah1, 0, 0, 0);

        // ---- Activations: each lane holds (az,ah) for rows q*4+i, col m / m+16.
        // Everything is summed in the end, so accumulate in-lane.
#pragma unroll
        for (int i = 0; i < 4; ++i) {
            {   // cols 0..15 -> W_lin[m]
                const float omz = __builtin_amdgcn_rcpf(1.0f + __expf(az0[i]));
                const float e2  = __expf(2.0f * ah0[i]);
                const float th  = 1.0f - 2.0f * __builtin_amdgcn_rcpf(e2 + 1.0f);
                float H = omz * th;
                H = H > 0.0f ? H : 0.0f;
                osum = fmaf(H, wl0, osum);
            }
            {   // cols 16..31 -> W_lin[m+16]
                const float omz = __builtin_amdgcn_rcpf(1.0f + __expf(az1[i]));
                const float e2  = __expf(2.0f * ah1[i]);
                const float th  = 1.0f - 2.0f * __builtin_amdgcn_rcpf(e2 + 1.0f);
                float H = omz * th;
                H = H > 0.0f ? H : 0.0f;
                osum = fmaf(H, wl1, osum);
            }
        }
    }

    // ---- Reduce: wave butterfly, then 4 partials via LDS ----
#pragma unroll
    for (int off = 32; off > 0; off >>= 1)
        osum += __shfl_down(osum, off, 64);
    __shared__ float part[4];
    if (lane == 0) part[wv] = osum;
    __syncthreads();
    if (t == 0)
        out[g] = (part[0] + part[1] + part[2] + part[3]) * (1.0f / (float)NPG)
               + w[1120];
}

__global__ __launch_bounds__(256) void gcn_main(
    const float* __restrict__ x, const float* __restrict__ w, float* __restrict__ out)
{
    gcn_body(x, w, out, blockIdx.x, threadIdx.x);
}

// Fallback if ws_size too small: stage weights in LDS per block.
__global__ __launch_bounds__(256) void gcn_main_lds(
    const float* __restrict__ x,
    const float* __restrict__ Wz, const float* __restrict__ bz,
    const float* __restrict__ Wh, const float* __restrict__ bh,
    const float* __restrict__ Wlin, const float* __restrict__ blin,
    float* __restrict__ out)
{
    __shared__ float w[WS_FLOATS];
    const int t = threadIdx.x;
#pragma unroll
    for (int i = t; i < 512; i += 256) {
        w[i]       = Wz[i] + Wz[1536 + i];
        w[512 + i] = Wh[i] + Wh[1536 + i];
    }
    if (t < HID) { w[1024 + t] = bz[t]; w[1056 + t] = bh[t]; w[1088 + t] = Wlin[t]; }
    if (t == 0)  w[1120] = blin[0];
    __syncthreads();
    gcn_body(x, w, out, blockIdx.x, t);
}

extern "C" void kernel_launch(void* const* d_in, const int* in_sizes, int n_in,
                              void* d_out, int out_size, void* d_ws, size_t ws_size,
                              hipStream_t stream)
{
    // 0:x 1:edge_index 2:edge_weight 3:batch 4:W_z 5:b_z 6:W_r 7:b_r 8:W_h 9:b_h 10:W_lin 11:b_lin
    const float* x    = (const float*)d_in[0];
    const float* Wz   = (const float*)d_in[4];
    const float* bz   = (const float*)d_in[5];
    const float* Wh   = (const float*)d_in[8];
    const float* bh   = (const float*)d_in[9];
    const float* Wlin = (const float*)d_in[10];
    const float* blin = (const float*)d_in[11];
    float* out = (float*)d_out;

    if (ws_size >= WS_FLOATS * sizeof(float)) {
        float* w = (float*)d_ws;
        prep_kernel<<<1, 512, 0, stream>>>(Wz, bz, Wh, bh, Wlin, blin, w);
        gcn_main<<<N_GRAPHS, NPG, 0, stream>>>(x, w, out);
    } else {
        gcn_main_lds<<<N_GRAPHS, NPG, 0, stream>>>(x, Wz, bz, Wh, bh, Wlin, blin, out);
    }
}

// Round 4
// 166.112 us; speedup vs baseline: 1.2612x; 1.2284x over previous
//
#include <hip/hip_runtime.h>

// Problem constants (from reference)
#define N_GRAPHS  4096
#define NPG       256      // nodes per graph (contiguous batch segments)
#define F_IN      16
#define HID       32
#define LOG2E     1.4426950408889634f

// d_ws layout:
//  bytes [0 .. 4095]  : 4 pre-packed f16 B fragments in MFMA lane layout.
//                       frag f (0=Z cols0-15, 1=Z cols16-31, 2=H cols0-15,
//                       3=H cols16-31), lane l: 16 bytes at f*1024 + l*16.
//                       Weights pre-scaled: Z by log2e, H by 2*log2e (so the
//                       activation kernel can use raw exp2).
//  floats [1024..1055]: bz * log2e
//  floats [1056..1087]: bh * 2*log2e
//  floats [1088..1119]: W_lin
//  float  [1120]      : b_lin
#define WS_FLOATS 1121

typedef _Float16 half8   __attribute__((ext_vector_type(8)));  // 4 VGPR MFMA A/B
typedef float    float4v __attribute__((ext_vector_type(4)));  // MFMA C/D

#if __has_builtin(__builtin_amdgcn_exp2f)
#define EXP2(x) __builtin_amdgcn_exp2f(x)
#else
#define EXP2(x) exp2f(x)
#endif

union FragU { uint4 u; half8 h; };

// B fragment for lane l (q=l>>4, m=l&15) of frag f. Our stacked B is
// [Wh16(rows 0..15); Wh16(rows 0..15)] so K=32 pairs with A=[Ah|Al]:
// quad q holds rows k=(q&1)*8+j. W element [r][c] at r*32+c (k-stride 1536).
__device__ __forceinline__ uint4 make_frag(int f, int l,
    const float* __restrict__ Wz, const float* __restrict__ Wh)
{
    const int q = l >> 4, m = l & 15;
    const int c = (f & 1) * 16 + m;
    const float s = (f < 2) ? LOG2E : 2.0f * LOG2E;
    const float* W = (f < 2) ? Wz : Wh;
    FragU u;
#pragma unroll
    for (int j = 0; j < 8; ++j) {
        const int k = (q & 1) * 8 + j;
        u.h[j] = (_Float16)((W[k * 32 + c] + W[1536 + k * 32 + c]) * s);
    }
    return u.u;
}

__global__ __launch_bounds__(256) void prep_kernel(
    const float* __restrict__ Wz, const float* __restrict__ bz,
    const float* __restrict__ Wh, const float* __restrict__ bh,
    const float* __restrict__ Wlin, const float* __restrict__ blin,
    float* __restrict__ w)
{
    const int t = threadIdx.x;                       // 256 threads, 1 block
    ((uint4*)w)[t] = make_frag(t >> 6, t & 63, Wz, Wh);
    if (t < HID) {
        w[1024 + t] = bz[t] * LOG2E;
        w[1056 + t] = bh[t] * (2.0f * LOG2E);
        w[1088 + t] = Wlin[t];
    }
    if (t == 0) w[1120] = blin[0];
}

// One (node, col) activation: omz*tanh merged into a single rcp.
// v = (e2-1) / ((1+e1)*(e2+1)); clamp keeps e2 finite (avoids inf*0 NaN).
__device__ __forceinline__ float gate_term(float az, float ah, float wl, float osum)
{
    const float e1 = EXP2(az);
    const float e2 = EXP2(fminf(ah, 126.0f));
    const float r  = __builtin_amdgcn_rcpf((1.0f + e1) * (e2 + 1.0f));
    float v = (e2 - 1.0f) * r;
    v = v > 0.0f ? v : 0.0f;                 // relu (omz>0, sign is tanh's)
    return fmaf(v, wl, osum);
}

// One block = one graph. Wave wv: nodes [wv*64, wv*64+64) as 4 MFMA tiles of
// 16 nodes. mfma_f32_16x16x32_f16, A=[Ah|Al] (hi + exact residual of x),
// B=[Bh;Bh] -> D = x*W exactly up to f16 weight rounding. One MFMA per acc.
// A layout: lane=(q<<4)|m holds A[m][k=q*8+j]; C/D: col=m, row=q*4+reg.
__device__ __forceinline__ void gcn_body(const float* __restrict__ x,
                                         const float* __restrict__ w,
                                         float* __restrict__ out, int g, int t)
{
    const int lane = t & 63, wv = t >> 6;
    const int q = lane >> 4, m = lane & 15;

    // B fragments: 4 coalesced 16B loads, already packed.
    const uint4* bq = (const uint4*)w;
    FragU u0, u1, u2, u3;
    u0.u = bq[lane];       u1.u = bq[64 + lane];
    u2.u = bq[128 + lane]; u3.u = bq[192 + lane];
    const half8 Bz0 = u0.h, Bz1 = u1.h, Bh0 = u2.h, Bh1 = u3.h;

    const float bz0 = w[1024 + m], bz1 = w[1040 + m];
    const float bh0 = w[1056 + m], bh1 = w[1072 + m];
    const float wl0 = w[1088 + m], wl1 = w[1104 + m];

    // Lane (q,m) loads features (q&1)*8..+8 of node it*16+m.
    // Quads 2,3 re-read quads 0,1's lines (L1 hit) and build the residual.
    const float* xw = x + ((size_t)g * NPG + wv * 64 + m) * F_IN + (q & 1) * 8;
    float4 c0 = *(const float4*)(xw);
    float4 c1 = *(const float4*)(xw + 4);
    const bool lo_lane = (q >= 2);
    float osum = 0.0f;

#pragma unroll
    for (int it = 0; it < 4; ++it) {
        float4 n0 = c0, n1 = c1;
        if (it < 3) {                              // prefetch next 16-node tile
            n0 = *(const float4*)(xw + (it + 1) * 256);
            n1 = *(const float4*)(xw + (it + 1) * 256 + 4);
        }
        const float xf[8] = { c0.x, c0.y, c0.z, c0.w, c1.x, c1.y, c1.z, c1.w };
        half8 A;
#pragma unroll
        for (int j = 0; j < 8; ++j) {
            _Float16 h = (_Float16)xf[j];                       // hi
            if (lo_lane) h = (_Float16)(xf[j] - (float)h);      // exact residual
            A[j] = h;
        }

        float4v az0 = { bz0, bz0, bz0, bz0 };
        float4v az1 = { bz1, bz1, bz1, bz1 };
        float4v ah0 = { bh0, bh0, bh0, bh0 };
        float4v ah1 = { bh1, bh1, bh1, bh1 };
        az0 = __builtin_amdgcn_mfma_f32_16x16x32_f16(A, Bz0, az0, 0, 0, 0);
        ah0 = __builtin_amdgcn_mfma_f32_16x16x32_f16(A, Bh0, ah0, 0, 0, 0);
        az1 = __builtin_amdgcn_mfma_f32_16x16x32_f16(A, Bz1, az1, 0, 0, 0);
        ah1 = __builtin_amdgcn_mfma_f32_16x16x32_f16(A, Bh1, ah1, 0, 0, 0);

#pragma unroll
        for (int i = 0; i < 4; ++i) {
            osum = gate_term(az0[i], ah0[i], wl0, osum);
            osum = gate_term(az1[i], ah1[i], wl1, osum);
        }
        c0 = n0; c1 = n1;
    }

    // Wave butterfly, then 4 partials via LDS.
#pragma unroll
    for (int off = 32; off > 0; off >>= 1)
        osum += __shfl_down(osum, off, 64);
    __shared__ float part[4];
    if (lane == 0) part[wv] = osum;
    __syncthreads();
    if (t == 0)
        out[g] = (part[0] + part[1] + part[2] + part[3]) * (1.0f / (float)NPG)
               + w[1120];
}

__global__ __launch_bounds__(256, 6) void gcn_main(
    const float* __restrict__ x, const float* __restrict__ w, float* __restrict__ out)
{
    gcn_body(x, w, out, blockIdx.x, threadIdx.x);
}

// Fallback if ws_size too small: build the same 1121-float image in LDS.
__global__ __launch_bounds__(256, 6) void gcn_main_lds(
    const float* __restrict__ x,
    const float* __restrict__ Wz, const float* __restrict__ bz,
    const float* __restrict__ Wh, const float* __restrict__ bh,
    const float* __restrict__ Wlin, const float* __restrict__ blin,
    float* __restrict__ out)
{
    __shared__ __attribute__((aligned(16))) float w[WS_FLOATS];
    const int t = threadIdx.x;
    ((uint4*)w)[t] = make_frag(t >> 6, t & 63, Wz, Wh);
    if (t < HID) {
        w[1024 + t] = bz[t] * LOG2E;
        w[1056 + t] = bh[t] * (2.0f * LOG2E);
        w[1088 + t] = Wlin[t];
    }
    if (t == 0) w[1120] = blin[0];
    __syncthreads();
    gcn_body(x, w, out, blockIdx.x, t);
}

extern "C" void kernel_launch(void* const* d_in, const int* in_sizes, int n_in,
                              void* d_out, int out_size, void* d_ws, size_t ws_size,
                              hipStream_t stream)
{
    // 0:x 1:edge_index 2:edge_weight 3:batch 4:W_z 5:b_z 6:W_r 7:b_r 8:W_h 9:b_h 10:W_lin 11:b_lin
    const float* x    = (const float*)d_in[0];
    const float* Wz   = (const float*)d_in[4];
    const float* bz   = (const float*)d_in[5];
    const float* Wh   = (const float*)d_in[8];
    const float* bh   = (const float*)d_in[9];
    const float* Wlin = (const float*)d_in[10];
    const float* blin = (const float*)d_in[11];
    float* out = (float*)d_out;

    if (ws_size >= WS_FLOATS * sizeof(float)) {
        float* w = (float*)d_ws;
        prep_kernel<<<1, 256, 0, stream>>>(Wz, bz, Wh, bh, Wlin, blin, w);
        gcn_main<<<N_GRAPHS, NPG, 0, stream>>>(x, w, out);
    } else {
        gcn_main_lds<<<N_GRAPHS, NPG, 0, stream>>>(x, Wz, bz, Wh, bh, Wlin, blin, out);
    }
}